// Round 5
// baseline (117.029 us; speedup 1.0000x reference)
//
#include <hip/hip_runtime.h>

// PCEN with 10 smoothing rates. x:(B,F,T) f32 -> out:(B,R,F,T) f32
//
// One wave owns one (b,rate,f) row of T=4000 (rate-major mapping: block's
// 4 waves write 4 consecutive 16KB output rows).
// y_t = a*y_{t-1} + s*x_t, y_0 = x_0 (seed carry=x_0, a+s=1).
// Per 512-element chunk: lane loads 8 floats (2x float4), local 8-elem scan,
// 6-step shuffle scan over lane carries (multipliers a^8..a^256),
// per-element fixup, PCEN epilogue via native exp2/log2.
//
// R5 = R3 minus nontemporal stores (single-variable A/B).
// Theory: lane*8 layout makes each store instr half-line-dense (32B stride);
// nt bypasses L2 write-combining -> ~2x HBM write transactions. Normal
// stores let L2 merge the two half-line stores into full 128B lines.
// R4 (5 rates/wave) regressed 90.8->100.5: TLP 20480->4096 waves + 5-way
// write-stream split per wave. Reverted.

typedef float f32x4 __attribute__((ext_vector_type(4)));

constexpr int B_ = 16, F_ = 128, T_ = 4000, R_ = 10;
constexpr float EPS_ = 1e-5f;
constexpr int TPB = 256;            // 4 waves / block
constexpr int WPB = TPB / 64;

__global__ __launch_bounds__(TPB) void pcen_kernel(
    const float* __restrict__ x,
    const float* __restrict__ s_log,
    const float* __restrict__ alpha_log,
    const float* __restrict__ delta_log,
    const float* __restrict__ r_log,
    float* __restrict__ out)
{
    const int wid  = blockIdx.x * WPB + (threadIdx.x >> 6);
    const int lane = threadIdx.x & 63;

    // rate-major: wid = ((b*R + rate)*F + f)
    const int b    = wid / (R_ * F_);
    const int rem  = wid - b * (R_ * F_);
    const int rate = rem / F_;
    const int f    = rem - rate * F_;

    const float s     = __builtin_expf(s_log[rate * F_ + f]);
    const float a     = 1.0f - s;
    const float alpha = __builtin_expf(alpha_log[f]);
    const float delta = __builtin_expf(delta_log[f]);
    const float r     = __builtin_expf(r_log[f]);
    const float delta_r = __builtin_exp2f(r * __builtin_log2f(delta));

    const float a2 = a * a,     a3 = a2 * a,    a4 = a2 * a2;
    const float a5 = a4 * a,    a6 = a4 * a2,   a7 = a4 * a3,   a8 = a4 * a4;
    const float a16 = a8 * a8,  a32 = a16 * a16, a64 = a32 * a32;
    const float a128 = a64 * a64, a256 = a128 * a128;

    const float* xrow = x   + (size_t)(b * F_ + f) * T_;
    float*       orow = out + (size_t)((b * R_ + rate) * F_ + f) * T_;

    float carry = xrow[0];   // y_{-1} := x_0  (a+s=1 makes y_0 = x_0)

    auto pcen1 = [&](float xv, float m) -> float {
        const float sm = __builtin_exp2f(-alpha * __builtin_log2f(EPS_ + m));
        return __builtin_exp2f(r * __builtin_log2f(fmaf(xv, sm, delta))) - delta_r;
    };

    for (int t0 = 0; t0 < T_; t0 += 512) {
        const int t = t0 + lane * 8;
        const bool act = (t < T_);           // T_ % 8 == 0: active lanes are full
        float4 v0 = make_float4(0.f, 0.f, 0.f, 0.f);
        float4 v1 = make_float4(0.f, 0.f, 0.f, 0.f);
        if (act) {
            v0 = *reinterpret_cast<const float4*>(xrow + t);
            v1 = *reinterpret_cast<const float4*>(xrow + t + 4);
        }

        // local scan with zero incoming state
        const float l0 = s * v0.x;
        const float l1 = fmaf(a, l0, s * v0.y);
        const float l2 = fmaf(a, l1, s * v0.z);
        const float l3 = fmaf(a, l2, s * v0.w);
        const float l4 = fmaf(a, l3, s * v1.x);
        const float l5 = fmaf(a, l4, s * v1.y);
        const float l6 = fmaf(a, l5, s * v1.z);
        const float l7 = fmaf(a, l6, s * v1.w);

        float Y = l7;
        if (lane == 0) Y = fmaf(a8, carry, Y);   // fold chunk carry into lane 0

        // Hillis-Steele inclusive scan, per-lane segment multiplier a^8
        float up;
        up = __shfl_up(Y, 1);  if (lane >= 1)  Y = fmaf(a8,   up, Y);
        up = __shfl_up(Y, 2);  if (lane >= 2)  Y = fmaf(a16,  up, Y);
        up = __shfl_up(Y, 4);  if (lane >= 4)  Y = fmaf(a32,  up, Y);
        up = __shfl_up(Y, 8);  if (lane >= 8)  Y = fmaf(a64,  up, Y);
        up = __shfl_up(Y, 16); if (lane >= 16) Y = fmaf(a128, up, Y);
        up = __shfl_up(Y, 32); if (lane >= 32) Y = fmaf(a256, up, Y);

        float yin = __shfl_up(Y, 1);
        if (lane == 0) yin = carry;
        carry = __shfl(Y, 63);                   // chunk-exit state, broadcast

        if (act) {
            const float m0 = fmaf(a,  yin, l0);
            const float m1 = fmaf(a2, yin, l1);
            const float m2 = fmaf(a3, yin, l2);
            const float m3 = fmaf(a4, yin, l3);
            const float m4 = fmaf(a5, yin, l4);
            const float m5 = fmaf(a6, yin, l5);
            const float m6 = fmaf(a7, yin, l6);
            const float m7 = fmaf(a8, yin, l7);

            f32x4 o0, o1;
            o0.x = pcen1(v0.x, m0);
            o0.y = pcen1(v0.y, m1);
            o0.z = pcen1(v0.z, m2);
            o0.w = pcen1(v0.w, m3);
            o1.x = pcen1(v1.x, m4);
            o1.y = pcen1(v1.y, m5);
            o1.z = pcen1(v1.z, m6);
            o1.w = pcen1(v1.w, m7);
            *reinterpret_cast<f32x4*>(orow + t)     = o0;   // normal cached stores:
            *reinterpret_cast<f32x4*>(orow + t + 4) = o1;   // L2 merges half-lines
        }
    }
}

extern "C" void kernel_launch(void* const* d_in, const int* in_sizes, int n_in,
                              void* d_out, int out_size, void* d_ws, size_t ws_size,
                              hipStream_t stream) {
    const float* x         = (const float*)d_in[0];
    const float* s_log     = (const float*)d_in[1];
    const float* alpha_log = (const float*)d_in[2];
    const float* delta_log = (const float*)d_in[3];
    const float* r_log     = (const float*)d_in[4];
    float* out = (float*)d_out;

    const int n_waves = B_ * R_ * F_;          // 20480
    const int blocks  = n_waves / WPB;         // 5120
    pcen_kernel<<<blocks, TPB, 0, stream>>>(x, s_log, alpha_log, delta_log, r_log, out);
}

// Round 6
// 91.499 us; speedup vs baseline: 1.2790x; 1.2790x over previous
//
#include <hip/hip_runtime.h>

// PCEN with 10 smoothing rates. x:(B,F,T) f32 -> out:(B,R,F,T) f32
//
// One wave owns one (b,rate,f) row (rate-major mapping). Recurrence
// y_t = a*y_{t-1} + s*x_t, y_0 = x_0 (seed carry=x_0, a+s=1).
//
// R6: dense-1KB memory ops + dual-chain scan.
//   Each 512-elem chunk = two 256-elem sub-chunks A,B; lane holds
//   [lane*4..+3] of EACH -> every load/store instruction covers a fully
//   dense 1KB burst (R3's lane*8 layout was 32B-strided = half-line-dense;
//   nt stores can't be merged -> ~2x HBM write amplification; 655MB/6.9TBs
//   = 95us ~= observed 90.8us).
//   A and B scan as independent 64-lane Hillis-Steele chains (2-way ILP on
//   the serial shuffle chain); B is linked to A analytically:
//   yinB += a^(4*lane)*exitA (exact per-lane power from lane bits),
//   carry' = a^256*exitA + exitB.
//   Stores stay nontemporal (R5 proved cached stores regress: 117us).

typedef float f32x4 __attribute__((ext_vector_type(4)));

constexpr int B_ = 16, F_ = 128, T_ = 4000, R_ = 10;
constexpr float EPS_ = 1e-5f;
constexpr int TPB = 256;            // 4 waves / block
constexpr int WPB = TPB / 64;

__global__ __launch_bounds__(TPB) void pcen_kernel(
    const float* __restrict__ x,
    const float* __restrict__ s_log,
    const float* __restrict__ alpha_log,
    const float* __restrict__ delta_log,
    const float* __restrict__ r_log,
    float* __restrict__ out)
{
    const int wid  = blockIdx.x * WPB + (threadIdx.x >> 6);
    const int lane = threadIdx.x & 63;

    // rate-major: wid = ((b*R + rate)*F + f) -> block's 4 waves write 4
    // consecutive 16KB output rows.
    const int b    = wid / (R_ * F_);
    const int rem  = wid - b * (R_ * F_);
    const int rate = rem / F_;
    const int f    = rem - rate * F_;

    const float s     = __builtin_expf(s_log[rate * F_ + f]);
    const float a     = 1.0f - s;
    const float alpha = __builtin_expf(alpha_log[f]);
    const float delta = __builtin_expf(delta_log[f]);
    const float r     = __builtin_expf(r_log[f]);
    const float delta_r = __builtin_exp2f(r * __builtin_log2f(delta));

    const float a2 = a * a, a3 = a2 * a, a4 = a2 * a2;
    const float a8 = a4 * a4, a16 = a8 * a8, a32 = a16 * a16;
    const float a64 = a32 * a32, a128 = a64 * a64, a256 = a128 * a128;

    // per-lane a^(4*lane), exact product over lane bits
    float pl = 1.0f;
    pl *= (lane & 1)  ? a4   : 1.0f;
    pl *= (lane & 2)  ? a8   : 1.0f;
    pl *= (lane & 4)  ? a16  : 1.0f;
    pl *= (lane & 8)  ? a32  : 1.0f;
    pl *= (lane & 16) ? a64  : 1.0f;
    pl *= (lane & 32) ? a128 : 1.0f;

    const float* xrow = x   + (size_t)(b * F_ + f) * T_;
    float*       orow = out + (size_t)((b * R_ + rate) * F_ + f) * T_;

    float carry = xrow[0];   // y_{-1} := x_0  (a+s=1 makes y_0 = x_0)

    auto pcen1 = [&](float xv, float m) -> float {
        const float sm = __builtin_exp2f(-alpha * __builtin_log2f(EPS_ + m));
        return __builtin_exp2f(r * __builtin_log2f(fmaf(xv, sm, delta))) - delta_r;
    };

    for (int t0 = 0; t0 < T_; t0 += 512) {
        const int tA = t0 + lane * 4;
        const int tB = tA + 256;
        const bool actA = (tA < T_);
        const bool actB = (tB < T_);
        float4 vA = make_float4(0.f, 0.f, 0.f, 0.f);
        float4 vB = make_float4(0.f, 0.f, 0.f, 0.f);
        if (actA) vA = *reinterpret_cast<const float4*>(xrow + tA);
        if (actB) vB = *reinterpret_cast<const float4*>(xrow + tB);

        // local zero-init scans (independent)
        const float lA0 = s * vA.x;
        const float lA1 = fmaf(a, lA0, s * vA.y);
        const float lA2 = fmaf(a, lA1, s * vA.z);
        const float lA3 = fmaf(a, lA2, s * vA.w);
        const float lB0 = s * vB.x;
        const float lB1 = fmaf(a, lB0, s * vB.y);
        const float lB2 = fmaf(a, lB1, s * vB.z);
        const float lB3 = fmaf(a, lB2, s * vB.w);

        float YA = lA3;
        if (lane == 0) YA = fmaf(a4, carry, YA);   // fold prev-chunk carry
        float YB = lB3;                             // zero-init chain

        // two interleaved Hillis-Steele scans, segment multiplier a^4
        float uA, uB;
        uA = __shfl_up(YA, 1);  uB = __shfl_up(YB, 1);
        if (lane >= 1)  { YA = fmaf(a4,   uA, YA); YB = fmaf(a4,   uB, YB); }
        uA = __shfl_up(YA, 2);  uB = __shfl_up(YB, 2);
        if (lane >= 2)  { YA = fmaf(a8,   uA, YA); YB = fmaf(a8,   uB, YB); }
        uA = __shfl_up(YA, 4);  uB = __shfl_up(YB, 4);
        if (lane >= 4)  { YA = fmaf(a16,  uA, YA); YB = fmaf(a16,  uB, YB); }
        uA = __shfl_up(YA, 8);  uB = __shfl_up(YB, 8);
        if (lane >= 8)  { YA = fmaf(a32,  uA, YA); YB = fmaf(a32,  uB, YB); }
        uA = __shfl_up(YA, 16); uB = __shfl_up(YB, 16);
        if (lane >= 16) { YA = fmaf(a64,  uA, YA); YB = fmaf(a64,  uB, YB); }
        uA = __shfl_up(YA, 32); uB = __shfl_up(YB, 32);
        if (lane >= 32) { YA = fmaf(a128, uA, YA); YB = fmaf(a128, uB, YB); }

        float yinA = __shfl_up(YA, 1);
        if (lane == 0) yinA = carry;
        float yinB = __shfl_up(YB, 1);
        if (lane == 0) yinB = 0.0f;
        const float exitA = __shfl(YA, 63);
        yinB = fmaf(pl, exitA, yinB);              // link chain B to chain A
        carry = fmaf(a256, exitA, __shfl(YB, 63)); // chunk-exit state

        if (actA) {
            const float mA0 = fmaf(a,  yinA, lA0);
            const float mA1 = fmaf(a2, yinA, lA1);
            const float mA2 = fmaf(a3, yinA, lA2);
            const float mA3 = fmaf(a4, yinA, lA3);
            f32x4 o;
            o.x = pcen1(vA.x, mA0);
            o.y = pcen1(vA.y, mA1);
            o.z = pcen1(vA.z, mA2);
            o.w = pcen1(vA.w, mA3);
            __builtin_nontemporal_store(o, reinterpret_cast<f32x4*>(orow + tA));
        }
        if (actB) {
            const float mB0 = fmaf(a,  yinB, lB0);
            const float mB1 = fmaf(a2, yinB, lB1);
            const float mB2 = fmaf(a3, yinB, lB2);
            const float mB3 = fmaf(a4, yinB, lB3);
            f32x4 o;
            o.x = pcen1(vB.x, mB0);
            o.y = pcen1(vB.y, mB1);
            o.z = pcen1(vB.z, mB2);
            o.w = pcen1(vB.w, mB3);
            __builtin_nontemporal_store(o, reinterpret_cast<f32x4*>(orow + tB));
        }
    }
}

extern "C" void kernel_launch(void* const* d_in, const int* in_sizes, int n_in,
                              void* d_out, int out_size, void* d_ws, size_t ws_size,
                              hipStream_t stream) {
    const float* x         = (const float*)d_in[0];
    const float* s_log     = (const float*)d_in[1];
    const float* alpha_log = (const float*)d_in[2];
    const float* delta_log = (const float*)d_in[3];
    const float* r_log     = (const float*)d_in[4];
    float* out = (float*)d_out;

    const int n_waves = B_ * R_ * F_;          // 20480
    const int blocks  = n_waves / WPB;         // 5120
    pcen_kernel<<<blocks, TPB, 0, stream>>>(x, s_log, alpha_log, delta_log, r_log, out);
}